// Round 22
// baseline (62.052 us; speedup 1.0000x reference)
//
#include <hip/hip_runtime.h>
#include <hip/hip_bf16.h>

// Problem: SelfAttention1d  B=4, L=2048, C=256, H=8, D=32.
// dtypes: inputs fp32, output fp32 (best = r20: 51.6us; r21 split-4 regressed).
// Round 22: r20 base (split-2 attn, pipelined qkv, staged proj) + attn
// prefetch depth 2: two named reg sets, unroll-2 loop -> each K/V load gets
// a full tile-window of flight time before its ds_write (r21 showed depth
// wasn't the chain; late-issued loads stalling WRITEB->barrier was).

typedef __bf16 bf16x4 __attribute__((ext_vector_type(4)));
typedef __bf16 bf16x8 __attribute__((ext_vector_type(8)));
typedef float  f32x4  __attribute__((ext_vector_type(4)));
typedef float  f32x16 __attribute__((ext_vector_type(16)));
typedef unsigned u32x4 __attribute__((ext_vector_type(4)));

#define MFMA16(a, b, c) __builtin_amdgcn_mfma_f32_16x16x32_bf16((a), (b), (c), 0, 0, 0)
#define MFMA32(a, b, c) __builtin_amdgcn_mfma_f32_32x32x16_bf16((a), (b), (c), 0, 0, 0)

static constexpr int Bsz = 4, L = 2048, C = 256, H = 8, D = 32;
static constexpr float SCALE = 0.17677669529663687f;   // 32^-0.5
static constexpr float LOG2E = 1.44269504088896f;
static constexpr float QSCALE = SCALE * LOG2E;         // exp2(S) = softmax exp

__device__ inline float fast_exp2(float x) {
#if __has_builtin(__builtin_amdgcn_exp2f)
    return __builtin_amdgcn_exp2f(x);
#else
    float r; asm("v_exp_f32 %0, %1" : "=v"(r) : "v"(x)); return r;
#endif
}

__device__ inline unsigned cvt_pk_bf16(float lo, float hi) {
    unsigned d;
    asm("v_cvt_pk_bf16_f32 %0, %1, %2" : "=v"(d) : "v"(lo), "v"(hi));
    return d;
}

// ---------------------------------------------------------------------------
// Kernel 1: QKV GEMM, LDS-staged, software-pipelined (r20, unchanged).
// ---------------------------------------------------------------------------
__global__ __launch_bounds__(256) void qkv_gemm(
    const float* __restrict__ X, const float* __restrict__ W,
    const float* __restrict__ Bq,
    __bf16* __restrict__ Qw, __bf16* __restrict__ Kw, __bf16* __restrict__ Vt)
{
    constexpr int LDK = 136;
    __shared__ __align__(16) __bf16 smem[128 * LDK + 64 * LDK];
    __bf16* Xs = smem;
    __bf16* Wsh = smem + 128 * LDK;

    const int bm = blockIdx.x & 63, bn = blockIdx.x >> 6;
    const int tid = threadIdx.x, wid = tid >> 6, lane = tid & 63;
    const int lr = lane & 15, lh = lane >> 4;
    const int m0b = bm * 128, n0b = bn * 64;
    const int wm0 = (wid >> 1) * 64, wn0 = (wid & 1) * 32;

    const int srow2 = lane >> 5;
    const int scol  = (lane & 31) * 4;

    f32x4 acc[4][2] = {};
    f32x4 xr[16], wr8[8];

#define LOADC(CH) do {                                                        \
    const int k0c = (CH) * 128;                                               \
    _Pragma("unroll")                                                         \
    for (int j = 0; j < 16; ++j) {                                            \
        const int row = j * 8 + wid * 2 + srow2;                              \
        xr[j] = *(const f32x4*)(X + (size_t)(m0b + row) * 256 + k0c + scol);  \
    }                                                                         \
    _Pragma("unroll")                                                         \
    for (int j = 0; j < 8; ++j) {                                             \
        const int row = j * 8 + wid * 2 + srow2;                              \
        wr8[j] = *(const f32x4*)(W + (size_t)(n0b + row) * 256 + k0c + scol); \
    }                                                                         \
} while (0)

#define WRITEC() do {                                                         \
    _Pragma("unroll")                                                         \
    for (int j = 0; j < 16; ++j) {                                            \
        const int row = j * 8 + wid * 2 + srow2;                              \
        bf16x4 cv; cv[0]=(__bf16)xr[j][0]; cv[1]=(__bf16)xr[j][1];            \
                   cv[2]=(__bf16)xr[j][2]; cv[3]=(__bf16)xr[j][3];            \
        *(bf16x4*)(&Xs[row * LDK + scol]) = cv;                               \
    }                                                                         \
    _Pragma("unroll")                                                         \
    for (int j = 0; j < 8; ++j) {                                             \
        const int row = j * 8 + wid * 2 + srow2;                              \
        bf16x4 cv; cv[0]=(__bf16)wr8[j][0]; cv[1]=(__bf16)wr8[j][1];          \
                   cv[2]=(__bf16)wr8[j][2]; cv[3]=(__bf16)wr8[j][3];          \
        *(bf16x4*)(&Wsh[row * LDK + scol]) = cv;                              \
    }                                                                         \
} while (0)

#define COMPUTEC() do {                                                       \
    _Pragma("unroll")                                                         \
    for (int ks = 0; ks < 4; ++ks) {                                          \
        bf16x8 a[4], b[2];                                                    \
        _Pragma("unroll")                                                     \
        for (int mt = 0; mt < 4; ++mt)                                        \
            a[mt] = *(const bf16x8*)(&Xs[(wm0 + mt * 16 + lr) * LDK + ks * 32 + lh * 8]); \
        _Pragma("unroll")                                                     \
        for (int nt = 0; nt < 2; ++nt)                                        \
            b[nt] = *(const bf16x8*)(&Wsh[(wn0 + nt * 16 + lr) * LDK + ks * 32 + lh * 8]); \
        _Pragma("unroll")                                                     \
        for (int mt = 0; mt < 4; ++mt)                                        \
            _Pragma("unroll")                                                 \
            for (int nt = 0; nt < 2; ++nt)                                    \
                acc[mt][nt] = MFMA16(a[mt], b[nt], acc[mt][nt]);              \
    }                                                                         \
} while (0)

    LOADC(0);
    WRITEC();
    LOADC(1);
    __syncthreads();
    COMPUTEC();
    __syncthreads();
    WRITEC();
    __syncthreads();
    COMPUTEC();
    __syncthreads();

#undef LOADC
#undef WRITEC
#undef COMPUTEC

    const int m0 = m0b + wm0;
    const int n0 = n0b + wn0;
    const int bb  = m0 >> 11;
    const int li0 = m0 & 2047;
    const int h = n0 / 96, r = n0 % 96;
    const int which = r >> 5;
    const int bh = bb * H + h;
    __bf16* sw = smem + wid * 2560;

    if (which == 2) {
        #pragma unroll
        for (int nt = 0; nt < 2; ++nt) {
            const float bias = Bq[n0 + nt * 16 + lr];
            #pragma unroll
            for (int mt = 0; mt < 4; ++mt)
                #pragma unroll
                for (int i = 0; i < 4; ++i)
                    sw[(nt * 16 + lr) * 72 + mt * 16 + lh * 4 + i] =
                        (__bf16)(acc[mt][nt][i] + bias);
        }
        #pragma unroll
        for (int j = 0; j < 4; ++j) {
            const int cch = lane + 64 * j;
            const int d = cch >> 3, lc = (cch & 7) * 8;
            const bf16x8 v = *(const bf16x8*)(&sw[d * 72 + lc]);
            *(bf16x8*)(Vt + ((size_t)bh * D + d) * L + li0 + lc) = v;
        }
    } else {
        const float scl = (which == 0) ? QSCALE : 1.0f;
        #pragma unroll
        for (int nt = 0; nt < 2; ++nt) {
            const float bias = Bq[n0 + nt * 16 + lr];
            #pragma unroll
            for (int mt = 0; mt < 4; ++mt)
                #pragma unroll
                for (int i = 0; i < 4; ++i)
                    sw[(mt * 16 + lh * 4 + i) * 40 + nt * 16 + lr] =
                        (__bf16)((acc[mt][nt][i] + bias) * scl);
        }
        __bf16* dst = (which == 0 ? Qw : Kw) + ((size_t)bh * L + li0) * D;
        #pragma unroll
        for (int j = 0; j < 4; ++j) {
            const int cch = lane + 64 * j;
            const bf16x8 v = *(const bf16x8*)(&sw[(cch >> 2) * 40 + (cch & 3) * 8]);
            *(bf16x8*)(dst + (size_t)cch * 8) = v;
        }
    }
}

// ---------------------------------------------------------------------------
// Kernel 2: flash attention, KV-split 2, 32x32x16 MFMA, in-register P (T12),
// prefetch depth 2 (two reg sets, unroll-2 loop).
// grid 1024 = 32 bh x 32 qt(64 rows); 256 thr (4 waves).
// ---------------------------------------------------------------------------
__global__ __launch_bounds__(256, 4) void attn_fwd(
    const __bf16* __restrict__ Qw, const __bf16* __restrict__ Kw,
    const __bf16* __restrict__ Vt, __bf16* __restrict__ O)
{
    __shared__ __align__(16) __bf16 smem[19456];

    const int bid = blockIdx.x;
    const int bh = ((bid & 7) << 2) | ((bid >> 3) & 3);
    const int qt = bid >> 5;
    const int tid = threadIdx.x, wid = tid >> 6, lane = tid & 63;
    const int lo = lane & 31, hi = lane >> 5;
    const int qgroup = wid & 1, khalf = wid >> 1;
    const int q0 = qt * 64 + qgroup * 32;

    const __bf16* Qb = Qw + (size_t)bh * L * D;
    const __bf16* Kb = Kw + (size_t)bh * L * D;
    const __bf16* Vb = Vt + (size_t)bh * D * L;

    bf16x8 qf[2];
    #pragma unroll
    for (int cl = 0; cl < 2; ++cl)
        qf[cl] = *(const bf16x8*)(Qb + (size_t)(q0 + lo) * D + cl * 16 + hi * 8);

    f32x16 oacc = {};
    float sacc[4] = {0.f, 0.f, 0.f, 0.f};

    const int krow = tid >> 1, kcol = (tid & 1) * 16;
    const int khS = krow >> 6, krl = krow & 63;
    const int vrow = tid >> 2, vcol = (tid & 3) * 16;
    const int vhS = vrow >> 5, vd = vrow & 31;

    // two named staging sets (compile-time indexed; rule #20)
    bf16x8 kA0, kB0, vA0, vB0, kA1, kB1, vA1, vB1;
#define LOADR(S, KV) do {                                                      \
    const __bf16* kp = Kb + (size_t)(khS * 1024 + (KV) + krl) * D + kcol;      \
    kA##S = *(const bf16x8*)kp;  kB##S = *(const bf16x8*)(kp + 8);             \
    const __bf16* vp = Vb + (size_t)vd * L + vhS * 1024 + (KV) + vcol;         \
    vA##S = *(const bf16x8*)vp;  vB##S = *(const bf16x8*)(vp + 8);             \
} while (0)
#define WRITEB(S, BUF) do {                                                    \
    __bf16* kp = smem + ((BUF) * 2 + khS) * 4864 + krl * 40 + kcol;            \
    *(bf16x8*)kp = kA##S;  *(bf16x8*)(kp + 8) = kB##S;                         \
    __bf16* vp = smem + ((BUF) * 2 + vhS) * 4864 + 2560 + vd * 72 + vcol;      \
    *(bf16x8*)vp = vA##S;  *(bf16x8*)(vp + 8) = vB##S;                         \
} while (0)

#define COMPUTE(CUR) do {                                                      \
    const __bf16* Kp = smem + ((CUR) * 2 + khalf) * 4864;                      \
    const __bf16* Vp = Kp + 2560;                                              \
    _Pragma("unroll")                                                          \
    for (int sub = 0; sub < 2; ++sub) {                                        \
        const int kb = sub * 32;                                               \
        f32x16 sst = {};                                                       \
        const bf16x8 ka0 = *(const bf16x8*)(Kp + (kb + lo) * 40 + hi * 8);     \
        const bf16x8 ka1 = *(const bf16x8*)(Kp + (kb + lo) * 40 + 16 + hi * 8);\
        sst = MFMA32(ka0, qf[0], sst);                                         \
        sst = MFMA32(ka1, qf[1], sst);                                         \
        float p[16];                                                           \
        _Pragma("unroll")                                                      \
        for (int r = 0; r < 16; ++r) p[r] = fast_exp2(sst[r]);                 \
        _Pragma("unroll")                                                      \
        for (int r = 0; r < 16; ++r) sacc[r & 3] += p[r];                      \
        unsigned pk[8];                                                        \
        _Pragma("unroll")                                                      \
        for (int j = 0; j < 8; ++j) pk[j] = cvt_pk_bf16(p[2 * j], p[2 * j + 1]); \
        unsigned a0 = pk[0], b0 = pk[2];                                       \
        unsigned a1 = pk[1], b1 = pk[3];                                       \
        unsigned c0 = pk[4], d0 = pk[6];                                       \
        unsigned c1 = pk[5], d1 = pk[7];                                       \
        asm("v_permlane32_swap_b32 %0, %1" : "+v"(a0), "+v"(b0));              \
        asm("v_permlane32_swap_b32 %0, %1" : "+v"(a1), "+v"(b1));              \
        asm("v_permlane32_swap_b32 %0, %1" : "+v"(c0), "+v"(d0));              \
        asm("v_permlane32_swap_b32 %0, %1" : "+v"(c1), "+v"(d1));              \
        const u32x4 f0 = {a0, a1, b0, b1};                                     \
        const u32x4 f1 = {c0, c1, d0, d1};                                     \
        const bf16x8 pf0 = __builtin_bit_cast(bf16x8, f0);                     \
        const bf16x8 pf1 = __builtin_bit_cast(bf16x8, f1);                     \
        const bf16x8 vb0 = *(const bf16x8*)(Vp + lo * 72 + kb + hi * 8);       \
        const bf16x8 vb1 = *(const bf16x8*)(Vp + lo * 72 + kb + 16 + hi * 8);  \
        oacc = MFMA32(pf0, vb0, oacc);                                         \
        oacc = MFMA32(pf1, vb1, oacc);                                         \
    }                                                                          \
} while (0)

    // prologue: tile0 -> set0 -> buf0; tile1 -> set1 (in flight)
    LOADR(0, 0);
    WRITEB(0, 0);
    LOADR(1, 64);

    #pragma unroll 1
    for (int t = 0; t < 16; t += 2) {
        // window t (even): compute buf0; write tile t+1; load tile t+2
        __syncthreads();
        if (t + 2 < 16) LOADR(0, (t + 2) * 64);
        COMPUTE(0);
        WRITEB(1, 1);                       // tile t+1 -> buf1
        // window t+1 (odd): compute buf1; write tile t+2; load tile t+3
        __syncthreads();
        if (t + 3 < 16) LOADR(1, (t + 3) * 64);
        COMPUTE(1);
        if (t + 2 < 16) WRITEB(0, 0);       // tile t+2 -> buf0
    }
#undef LOADR
#undef WRITEB
#undef COMPUTE

    float tot = (sacc[0] + sacc[1]) + (sacc[2] + sacc[3]);
    tot += __shfl_xor(tot, 32);

    __syncthreads();
    float* cs = (float*)smem;
    if (khalf == 1) {
        float* p = cs + (qgroup * 64 + lane) * 20;
        #pragma unroll
        for (int r = 0; r < 16; ++r) p[r] = oacc[r];
        p[16] = tot;
    }
    __syncthreads();
    if (khalf == 0) {
        const float* p = cs + (qgroup * 64 + lane) * 20;
        #pragma unroll
        for (int r = 0; r < 16; ++r) oacc[r] += p[r];
        tot += p[16];
        const float inv = 1.f / tot;

        const int b = bh >> 3, h = bh & 7;
        #pragma unroll
        for (int r = 0; r < 16; ++r) {
            const int qr = (r & 3) + 8 * (r >> 2) + 4 * hi;
            const float rs = __shfl(inv, qr);
            O[((size_t)b * L + q0 + qr) * C + h * D + lo] = (__bf16)(oacc[r] * rs);
        }
    }
}

// ---------------------------------------------------------------------------
// Kernel 3: output projection with dense LDS staging (r19, unchanged).
// ---------------------------------------------------------------------------
__global__ __launch_bounds__(256) void proj_gemm(
    const __bf16* __restrict__ A, const float* __restrict__ W,
    const float* __restrict__ Bp, float* __restrict__ Out)
{
    constexpr int LDA = 264;
    __shared__ __align__(16) __bf16 ps[2 * 64 * LDA];
    __bf16* As = ps;
    __bf16* Wsb = ps + 64 * LDA;

    const int bm = blockIdx.x & 127, bn = blockIdx.x >> 7;
    const int tid = threadIdx.x, wid = tid >> 6, lane = tid & 63;
    const int lr = lane & 15, lh = lane >> 4;
    const int m0b = bm * 64, n0b = bn * 64;
    const int wm0 = (wid >> 1) * 32, wn0 = (wid & 1) * 32;

    #pragma unroll
    for (int j = 0; j < 8; ++j) {
        const int c = tid + 256 * j;
        const int row = c >> 5, col = (c & 31) * 8;
        *(bf16x8*)(&As[row * LDA + col]) =
            *(const bf16x8*)(A + (size_t)(m0b + row) * 256 + col);
    }
    #pragma unroll
    for (int j = 0; j < 16; ++j) {
        const int c = tid + 256 * j;
        const int row = c >> 6, col = (c & 63) * 4;
        const f32x4 v = *(const f32x4*)(W + (size_t)(n0b + row) * 256 + col);
        bf16x4 cv; cv[0]=(__bf16)v[0]; cv[1]=(__bf16)v[1]; cv[2]=(__bf16)v[2]; cv[3]=(__bf16)v[3];
        *(bf16x4*)(&Wsb[row * LDA + col]) = cv;
    }
    __syncthreads();

    f32x4 acc[2][2] = {};
    #pragma unroll
    for (int k0 = 0; k0 < 256; k0 += 32) {
        bf16x8 a[2], b[2];
        #pragma unroll
        for (int mt = 0; mt < 2; ++mt)
            a[mt] = *(const bf16x8*)(&As[(wm0 + mt * 16 + lr) * LDA + k0 + lh * 8]);
        #pragma unroll
        for (int nt = 0; nt < 2; ++nt)
            b[nt] = *(const bf16x8*)(&Wsb[(wn0 + nt * 16 + lr) * LDA + k0 + lh * 8]);
        #pragma unroll
        for (int mt = 0; mt < 2; ++mt)
            #pragma unroll
            for (int nt = 0; nt < 2; ++nt)
                acc[mt][nt] = MFMA16(a[mt], b[nt], acc[mt][nt]);
    }

    #pragma unroll
    for (int mt = 0; mt < 2; ++mt) {
        #pragma unroll
        for (int nt = 0; nt < 2; ++nt) {
            const int n = n0b + wn0 + nt * 16 + lr;
            const float bias = Bp[n];
            #pragma unroll
            for (int i = 0; i < 4; ++i) {
                const int m = m0b + wm0 + mt * 16 + lh * 4 + i;
                Out[(size_t)m * 256 + n] = acc[mt][nt][i] + bias;
            }
        }
    }
}

__global__ void fatal_flag(float* Out, int n, float v) {
    int i = blockIdx.x * blockDim.x + threadIdx.x;
    if (i < n) Out[i] = (i == 0) ? v : 0.f;
}

// ---------------------------------------------------------------------------
extern "C" void kernel_launch(void* const* d_in, const int* in_sizes, int n_in,
                              void* d_out, int out_size, void* d_ws, size_t ws_size,
                              hipStream_t stream)
{
    float* out = (float*)d_out;

    const float *x = nullptr, *w_qkv = nullptr, *b_qkv = nullptr,
                *w_proj = nullptr, *b_proj = nullptr;
    for (int i = 0; i < n_in; ++i) {
        switch (in_sizes[i]) {
            case 2097152: x      = (const float*)d_in[i]; break;
            case 196608:  w_qkv  = (const float*)d_in[i]; break;
            case 768:     b_qkv  = (const float*)d_in[i]; break;
            case 65536:   w_proj = (const float*)d_in[i]; break;
            case 256:     b_proj = (const float*)d_in[i]; break;
        }
    }
    if (!x || !w_qkv || !b_qkv || !w_proj || !b_proj) {
        fatal_flag<<<dim3((out_size + 255) / 256), dim3(256), 0, stream>>>(out, out_size, 3e9f);
        return;
    }

    const size_t SEG = (size_t)Bsz * H * L * D;      // 2M elems
    if (ws_size < 4 * SEG * sizeof(__bf16)) {
        fatal_flag<<<dim3((out_size + 255) / 256), dim3(256), 0, stream>>>(out, out_size, 1e9f);
        return;
    }

    __bf16* ws = (__bf16*)d_ws;
    __bf16* Qw = ws;
    __bf16* Kw = ws + SEG;
    __bf16* Vt = ws + 2 * SEG;
    __bf16* Ob = ws + 3 * SEG;

    qkv_gemm<<<dim3(768), dim3(256), 0, stream>>>(x, w_qkv, b_qkv, Qw, Kw, Vt);
    attn_fwd<<<dim3(1024), dim3(256), 0, stream>>>(Qw, Kw, Vt, Ob);
    proj_gemm<<<dim3(512), dim3(256), 0, stream>>>(Ob, w_proj, b_proj, out);
}

// Round 23
// 51.706 us; speedup vs baseline: 1.2001x; 1.2001x over previous
//
#include <hip/hip_runtime.h>
#include <hip/hip_bf16.h>

// Problem: SelfAttention1d  B=4, L=2048, C=256, H=8, D=32.
// dtypes: inputs fp32, output fp32.
// Round 23: RESTORE r20 (best: 51.6us). r21 (split-4) and r22 (depth-2
// prefetch) both regressed; r22's WRITE_SIZE=53MB revealed scratch spills.
// r20 = split-2 attn (32x32 MFMA, in-register P via cvt_pk+permlane32_swap,
// single-set issue-early K/V prefetch), software-pipelined qkv, staged proj.

typedef __bf16 bf16x4 __attribute__((ext_vector_type(4)));
typedef __bf16 bf16x8 __attribute__((ext_vector_type(8)));
typedef float  f32x4  __attribute__((ext_vector_type(4)));
typedef float  f32x16 __attribute__((ext_vector_type(16)));
typedef unsigned u32x4 __attribute__((ext_vector_type(4)));

#define MFMA16(a, b, c) __builtin_amdgcn_mfma_f32_16x16x32_bf16((a), (b), (c), 0, 0, 0)
#define MFMA32(a, b, c) __builtin_amdgcn_mfma_f32_32x32x16_bf16((a), (b), (c), 0, 0, 0)

static constexpr int Bsz = 4, L = 2048, C = 256, H = 8, D = 32;
static constexpr float SCALE = 0.17677669529663687f;   // 32^-0.5
static constexpr float LOG2E = 1.44269504088896f;
static constexpr float QSCALE = SCALE * LOG2E;         // exp2(S) = softmax exp

__device__ inline float fast_exp2(float x) {
#if __has_builtin(__builtin_amdgcn_exp2f)
    return __builtin_amdgcn_exp2f(x);
#else
    float r; asm("v_exp_f32 %0, %1" : "=v"(r) : "v"(x)); return r;
#endif
}

__device__ inline unsigned cvt_pk_bf16(float lo, float hi) {
    unsigned d;
    asm("v_cvt_pk_bf16_f32 %0, %1, %2" : "=v"(d) : "v"(lo), "v"(hi));
    return d;
}

// ---------------------------------------------------------------------------
// Kernel 1: QKV GEMM, LDS-staged, software-pipelined (r20).
// ---------------------------------------------------------------------------
__global__ __launch_bounds__(256) void qkv_gemm(
    const float* __restrict__ X, const float* __restrict__ W,
    const float* __restrict__ Bq,
    __bf16* __restrict__ Qw, __bf16* __restrict__ Kw, __bf16* __restrict__ Vt)
{
    constexpr int LDK = 136;
    __shared__ __align__(16) __bf16 smem[128 * LDK + 64 * LDK];
    __bf16* Xs = smem;
    __bf16* Wsh = smem + 128 * LDK;

    const int bm = blockIdx.x & 63, bn = blockIdx.x >> 6;
    const int tid = threadIdx.x, wid = tid >> 6, lane = tid & 63;
    const int lr = lane & 15, lh = lane >> 4;
    const int m0b = bm * 128, n0b = bn * 64;
    const int wm0 = (wid >> 1) * 64, wn0 = (wid & 1) * 32;

    const int srow2 = lane >> 5;
    const int scol  = (lane & 31) * 4;

    f32x4 acc[4][2] = {};
    f32x4 xr[16], wr8[8];

#define LOADC(CH) do {                                                        \
    const int k0c = (CH) * 128;                                               \
    _Pragma("unroll")                                                         \
    for (int j = 0; j < 16; ++j) {                                            \
        const int row = j * 8 + wid * 2 + srow2;                              \
        xr[j] = *(const f32x4*)(X + (size_t)(m0b + row) * 256 + k0c + scol);  \
    }                                                                         \
    _Pragma("unroll")                                                         \
    for (int j = 0; j < 8; ++j) {                                             \
        const int row = j * 8 + wid * 2 + srow2;                              \
        wr8[j] = *(const f32x4*)(W + (size_t)(n0b + row) * 256 + k0c + scol); \
    }                                                                         \
} while (0)

#define WRITEC() do {                                                         \
    _Pragma("unroll")                                                         \
    for (int j = 0; j < 16; ++j) {                                            \
        const int row = j * 8 + wid * 2 + srow2;                              \
        bf16x4 cv; cv[0]=(__bf16)xr[j][0]; cv[1]=(__bf16)xr[j][1];            \
                   cv[2]=(__bf16)xr[j][2]; cv[3]=(__bf16)xr[j][3];            \
        *(bf16x4*)(&Xs[row * LDK + scol]) = cv;                               \
    }                                                                         \
    _Pragma("unroll")                                                         \
    for (int j = 0; j < 8; ++j) {                                             \
        const int row = j * 8 + wid * 2 + srow2;                              \
        bf16x4 cv; cv[0]=(__bf16)wr8[j][0]; cv[1]=(__bf16)wr8[j][1];          \
                   cv[2]=(__bf16)wr8[j][2]; cv[3]=(__bf16)wr8[j][3];          \
        *(bf16x4*)(&Wsh[row * LDK + scol]) = cv;                              \
    }                                                                         \
} while (0)

#define COMPUTEC() do {                                                       \
    _Pragma("unroll")                                                         \
    for (int ks = 0; ks < 4; ++ks) {                                          \
        bf16x8 a[4], b[2];                                                    \
        _Pragma("unroll")                                                     \
        for (int mt = 0; mt < 4; ++mt)                                        \
            a[mt] = *(const bf16x8*)(&Xs[(wm0 + mt * 16 + lr) * LDK + ks * 32 + lh * 8]); \
        _Pragma("unroll")                                                     \
        for (int nt = 0; nt < 2; ++nt)                                        \
            b[nt] = *(const bf16x8*)(&Wsh[(wn0 + nt * 16 + lr) * LDK + ks * 32 + lh * 8]); \
        _Pragma("unroll")                                                     \
        for (int mt = 0; mt < 4; ++mt)                                        \
            _Pragma("unroll")                                                 \
            for (int nt = 0; nt < 2; ++nt)                                    \
                acc[mt][nt] = MFMA16(a[mt], b[nt], acc[mt][nt]);              \
    }                                                                         \
} while (0)

    LOADC(0);
    WRITEC();
    LOADC(1);                 // issue chunk-1 loads; in flight during compute0
    __syncthreads();
    COMPUTEC();               // chunk 0
    __syncthreads();
    WRITEC();                 // vmcnt drained during compute0
    __syncthreads();
    COMPUTEC();               // chunk 1
    __syncthreads();          // all LDS reads done before epilogue scratch

#undef LOADC
#undef WRITEC
#undef COMPUTEC

    const int m0 = m0b + wm0;
    const int n0 = n0b + wn0;
    const int bb  = m0 >> 11;
    const int li0 = m0 & 2047;
    const int h = n0 / 96, r = n0 % 96;
    const int which = r >> 5;
    const int bh = bb * H + h;
    __bf16* sw = smem + wid * 2560;

    if (which == 2) {
        #pragma unroll
        for (int nt = 0; nt < 2; ++nt) {
            const float bias = Bq[n0 + nt * 16 + lr];
            #pragma unroll
            for (int mt = 0; mt < 4; ++mt)
                #pragma unroll
                for (int i = 0; i < 4; ++i)
                    sw[(nt * 16 + lr) * 72 + mt * 16 + lh * 4 + i] =
                        (__bf16)(acc[mt][nt][i] + bias);
        }
        #pragma unroll
        for (int j = 0; j < 4; ++j) {
            const int cch = lane + 64 * j;
            const int d = cch >> 3, lc = (cch & 7) * 8;
            const bf16x8 v = *(const bf16x8*)(&sw[d * 72 + lc]);
            *(bf16x8*)(Vt + ((size_t)bh * D + d) * L + li0 + lc) = v;
        }
    } else {
        const float scl = (which == 0) ? QSCALE : 1.0f;
        #pragma unroll
        for (int nt = 0; nt < 2; ++nt) {
            const float bias = Bq[n0 + nt * 16 + lr];
            #pragma unroll
            for (int mt = 0; mt < 4; ++mt)
                #pragma unroll
                for (int i = 0; i < 4; ++i)
                    sw[(mt * 16 + lh * 4 + i) * 40 + nt * 16 + lr] =
                        (__bf16)((acc[mt][nt][i] + bias) * scl);
        }
        __bf16* dst = (which == 0 ? Qw : Kw) + ((size_t)bh * L + li0) * D;
        #pragma unroll
        for (int j = 0; j < 4; ++j) {
            const int cch = lane + 64 * j;
            const bf16x8 v = *(const bf16x8*)(&sw[(cch >> 2) * 40 + (cch & 3) * 8]);
            *(bf16x8*)(dst + (size_t)cch * 8) = v;
        }
    }
}

// ---------------------------------------------------------------------------
// Kernel 2: flash attention, KV-split 2, 32x32x16 MFMA, in-register P (T12).
// grid 1024 = 32 bh x 32 qt(64 rows); 256 thr (4 waves).
// Wave (qgroup=wid&1, khalf=wid>>1): q-rows qt*64+qgroup*32, keys
// [khalf*1024, +1024). Single-set issue-early prefetch (r20).
// ---------------------------------------------------------------------------
__global__ __launch_bounds__(256, 4) void attn_fwd(
    const __bf16* __restrict__ Qw, const __bf16* __restrict__ Kw,
    const __bf16* __restrict__ Vt, __bf16* __restrict__ O)
{
    __shared__ __align__(16) __bf16 smem[19456];

    const int bid = blockIdx.x;
    const int bh = ((bid & 7) << 2) | ((bid >> 3) & 3);
    const int qt = bid >> 5;
    const int tid = threadIdx.x, wid = tid >> 6, lane = tid & 63;
    const int lo = lane & 31, hi = lane >> 5;
    const int qgroup = wid & 1, khalf = wid >> 1;
    const int q0 = qt * 64 + qgroup * 32;

    const __bf16* Qb = Qw + (size_t)bh * L * D;
    const __bf16* Kb = Kw + (size_t)bh * L * D;
    const __bf16* Vb = Vt + (size_t)bh * D * L;

    bf16x8 qf[2];
    #pragma unroll
    for (int cl = 0; cl < 2; ++cl)
        qf[cl] = *(const bf16x8*)(Qb + (size_t)(q0 + lo) * D + cl * 16 + hi * 8);

    f32x16 oacc = {};
    float sacc[4] = {0.f, 0.f, 0.f, 0.f};

    const int krow = tid >> 1, kcol = (tid & 1) * 16;
    const int khS = krow >> 6, krl = krow & 63;
    const int vrow = tid >> 2, vcol = (tid & 3) * 16;
    const int vhS = vrow >> 5, vd = vrow & 31;

    bf16x8 kA, kB, vA, vB;
#define LOADR(KV) do {                                                         \
    const __bf16* kp = Kb + (size_t)(khS * 1024 + (KV) + krl) * D + kcol;      \
    kA = *(const bf16x8*)kp;  kB = *(const bf16x8*)(kp + 8);                   \
    const __bf16* vp = Vb + (size_t)vd * L + vhS * 1024 + (KV) + vcol;         \
    vA = *(const bf16x8*)vp;  vB = *(const bf16x8*)(vp + 8);                   \
} while (0)
#define WRITEB(BUF) do {                                                       \
    __bf16* kp = smem + ((BUF) * 2 + khS) * 4864 + krl * 40 + kcol;            \
    *(bf16x8*)kp = kA;  *(bf16x8*)(kp + 8) = kB;                               \
    __bf16* vp = smem + ((BUF) * 2 + vhS) * 4864 + 2560 + vd * 72 + vcol;      \
    *(bf16x8*)vp = vA;  *(bf16x8*)(vp + 8) = vB;                               \
} while (0)

    LOADR(0);
    WRITEB(0);

    for (int t = 0; t < 16; ++t) {
        const int cur = t & 1;
        if (t + 1 < 16) LOADR((t + 1) * 64);
        __syncthreads();

        const __bf16* Kp = smem + (cur * 2 + khalf) * 4864;
        const __bf16* Vp = Kp + 2560;

        #pragma unroll
        for (int sub = 0; sub < 2; ++sub) {
            const int kb = sub * 32;

            f32x16 sst = {};
            const bf16x8 ka0 = *(const bf16x8*)(Kp + (kb + lo) * 40 + hi * 8);
            const bf16x8 ka1 = *(const bf16x8*)(Kp + (kb + lo) * 40 + 16 + hi * 8);
            sst = MFMA32(ka0, qf[0], sst);
            sst = MFMA32(ka1, qf[1], sst);

            float p[16];
            #pragma unroll
            for (int r = 0; r < 16; ++r) p[r] = fast_exp2(sst[r]);
            #pragma unroll
            for (int r = 0; r < 16; ++r) sacc[r & 3] += p[r];

            unsigned pk[8];
            #pragma unroll
            for (int j = 0; j < 8; ++j) pk[j] = cvt_pk_bf16(p[2 * j], p[2 * j + 1]);

            unsigned a0 = pk[0], b0 = pk[2];
            unsigned a1 = pk[1], b1 = pk[3];
            unsigned c0 = pk[4], d0 = pk[6];
            unsigned c1 = pk[5], d1 = pk[7];
            asm("v_permlane32_swap_b32 %0, %1" : "+v"(a0), "+v"(b0));
            asm("v_permlane32_swap_b32 %0, %1" : "+v"(a1), "+v"(b1));
            asm("v_permlane32_swap_b32 %0, %1" : "+v"(c0), "+v"(d0));
            asm("v_permlane32_swap_b32 %0, %1" : "+v"(c1), "+v"(d1));
            const u32x4 f0 = {a0, a1, b0, b1};
            const u32x4 f1 = {c0, c1, d0, d1};
            const bf16x8 pf0 = __builtin_bit_cast(bf16x8, f0);
            const bf16x8 pf1 = __builtin_bit_cast(bf16x8, f1);

            const bf16x8 vb0 = *(const bf16x8*)(Vp + lo * 72 + kb + hi * 8);
            const bf16x8 vb1 = *(const bf16x8*)(Vp + lo * 72 + kb + 16 + hi * 8);
            oacc = MFMA32(pf0, vb0, oacc);
            oacc = MFMA32(pf1, vb1, oacc);
        }

        if (t + 1 < 16) WRITEB(cur ^ 1);
    }
#undef LOADR
#undef WRITEB

    float tot = (sacc[0] + sacc[1]) + (sacc[2] + sacc[3]);
    tot += __shfl_xor(tot, 32);

    __syncthreads();
    float* cs = (float*)smem;
    if (khalf == 1) {
        float* p = cs + (qgroup * 64 + lane) * 20;
        #pragma unroll
        for (int r = 0; r < 16; ++r) p[r] = oacc[r];
        p[16] = tot;
    }
    __syncthreads();
    if (khalf == 0) {
        const float* p = cs + (qgroup * 64 + lane) * 20;
        #pragma unroll
        for (int r = 0; r < 16; ++r) oacc[r] += p[r];
        tot += p[16];
        const float inv = 1.f / tot;

        const int b = bh >> 3, h = bh & 7;
        #pragma unroll
        for (int r = 0; r < 16; ++r) {
            const int qr = (r & 3) + 8 * (r >> 2) + 4 * hi;
            const float rs = __shfl(inv, qr);
            O[((size_t)b * L + q0 + qr) * C + h * D + lo] = (__bf16)(oacc[r] * rs);
        }
    }
}

// ---------------------------------------------------------------------------
// Kernel 3: output projection with dense LDS staging (r19).
// ---------------------------------------------------------------------------
__global__ __launch_bounds__(256) void proj_gemm(
    const __bf16* __restrict__ A, const float* __restrict__ W,
    const float* __restrict__ Bp, float* __restrict__ Out)
{
    constexpr int LDA = 264;
    __shared__ __align__(16) __bf16 ps[2 * 64 * LDA];
    __bf16* As = ps;
    __bf16* Wsb = ps + 64 * LDA;

    const int bm = blockIdx.x & 127, bn = blockIdx.x >> 7;
    const int tid = threadIdx.x, wid = tid >> 6, lane = tid & 63;
    const int lr = lane & 15, lh = lane >> 4;
    const int m0b = bm * 64, n0b = bn * 64;
    const int wm0 = (wid >> 1) * 32, wn0 = (wid & 1) * 32;

    #pragma unroll
    for (int j = 0; j < 8; ++j) {
        const int c = tid + 256 * j;
        const int row = c >> 5, col = (c & 31) * 8;
        *(bf16x8*)(&As[row * LDA + col]) =
            *(const bf16x8*)(A + (size_t)(m0b + row) * 256 + col);
    }
    #pragma unroll
    for (int j = 0; j < 16; ++j) {
        const int c = tid + 256 * j;
        const int row = c >> 6, col = (c & 63) * 4;
        const f32x4 v = *(const f32x4*)(W + (size_t)(n0b + row) * 256 + col);
        bf16x4 cv; cv[0]=(__bf16)v[0]; cv[1]=(__bf16)v[1]; cv[2]=(__bf16)v[2]; cv[3]=(__bf16)v[3];
        *(bf16x4*)(&Wsb[row * LDA + col]) = cv;
    }
    __syncthreads();

    f32x4 acc[2][2] = {};
    #pragma unroll
    for (int k0 = 0; k0 < 256; k0 += 32) {
        bf16x8 a[2], b[2];
        #pragma unroll
        for (int mt = 0; mt < 2; ++mt)
            a[mt] = *(const bf16x8*)(&As[(wm0 + mt * 16 + lr) * LDA + k0 + lh * 8]);
        #pragma unroll
        for (int nt = 0; nt < 2; ++nt)
            b[nt] = *(const bf16x8*)(&Wsb[(wn0 + nt * 16 + lr) * LDA + k0 + lh * 8]);
        #pragma unroll
        for (int mt = 0; mt < 2; ++mt)
            #pragma unroll
            for (int nt = 0; nt < 2; ++nt)
                acc[mt][nt] = MFMA16(a[mt], b[nt], acc[mt][nt]);
    }

    #pragma unroll
    for (int mt = 0; mt < 2; ++mt) {
        #pragma unroll
        for (int nt = 0; nt < 2; ++nt) {
            const int n = n0b + wn0 + nt * 16 + lr;
            const float bias = Bp[n];
            #pragma unroll
            for (int i = 0; i < 4; ++i) {
                const int m = m0b + wm0 + mt * 16 + lh * 4 + i;
                Out[(size_t)m * 256 + n] = acc[mt][nt][i] + bias;
            }
        }
    }
}

__global__ void fatal_flag(float* Out, int n, float v) {
    int i = blockIdx.x * blockDim.x + threadIdx.x;
    if (i < n) Out[i] = (i == 0) ? v : 0.f;
}

// ---------------------------------------------------------------------------
extern "C" void kernel_launch(void* const* d_in, const int* in_sizes, int n_in,
                              void* d_out, int out_size, void* d_ws, size_t ws_size,
                              hipStream_t stream)
{
    float* out = (float*)d_out;

    const float *x = nullptr, *w_qkv = nullptr, *b_qkv = nullptr,
                *w_proj = nullptr, *b_proj = nullptr;
    for (int i = 0; i < n_in; ++i) {
        switch (in_sizes[i]) {
            case 2097152: x      = (const float*)d_in[i]; break;
            case 196608:  w_qkv  = (const float*)d_in[i]; break;
            case 768:     b_qkv  = (const float*)d_in[i]; break;
            case 65536:   w_proj = (const float*)d_in[i]; break;
            case 256:     b_proj = (const float*)d_in[i]; break;
        }
    }
    if (!x || !w_qkv || !b_qkv || !w_proj || !b_proj) {
        fatal_flag<<<dim3((out_size + 255) / 256), dim3(256), 0, stream>>>(out, out_size, 3e9f);
        return;
    }

    const size_t SEG = (size_t)Bsz * H * L * D;      // 2M elems
    if (ws_size < 4 * SEG * sizeof(__bf16)) {
        fatal_flag<<<dim3((out_size + 255) / 256), dim3(256), 0, stream>>>(out, out_size, 1e9f);
        return;
    }

    __bf16* ws = (__bf16*)d_ws;
    __bf16* Qw = ws;
    __bf16* Kw = ws + SEG;
    __bf16* Vt = ws + 2 * SEG;
    __bf16* Ob = ws + 3 * SEG;

    qkv_gemm<<<dim3(768), dim3(256), 0, stream>>>(x, w_qkv, b_qkv, Qw, Kw, Vt);
    attn_fwd<<<dim3(1024), dim3(256), 0, stream>>>(Qw, Kw, Vt, Ob);
    proj_gemm<<<dim3(512), dim3(256), 0, stream>>>(Ob, w_proj, b_proj, out);
}

// Round 24
// 50.808 us; speedup vs baseline: 1.2213x; 1.0177x over previous
//
#include <hip/hip_runtime.h>
#include <hip/hip_bf16.h>

// Problem: SelfAttention1d  B=4, L=2048, C=256, H=8, D=32.
// dtypes: inputs fp32, output fp32. Best = r20/r23: 51.6/51.7us.
// Round 24: load-issue placement probe — prefetch loads moved AFTER the
// barrier (attn: bar->LOADR->COMPUTE->WRITEB; qkv: LOADC(1) after 1st bar).
// Guarantees full compute-phase flight before the consuming ds_write's
// vmcnt wait; no extra registers (r22 spill lesson). Everything else = r23.

typedef __bf16 bf16x4 __attribute__((ext_vector_type(4)));
typedef __bf16 bf16x8 __attribute__((ext_vector_type(8)));
typedef float  f32x4  __attribute__((ext_vector_type(4)));
typedef float  f32x16 __attribute__((ext_vector_type(16)));
typedef unsigned u32x4 __attribute__((ext_vector_type(4)));

#define MFMA16(a, b, c) __builtin_amdgcn_mfma_f32_16x16x32_bf16((a), (b), (c), 0, 0, 0)
#define MFMA32(a, b, c) __builtin_amdgcn_mfma_f32_32x32x16_bf16((a), (b), (c), 0, 0, 0)

static constexpr int Bsz = 4, L = 2048, C = 256, H = 8, D = 32;
static constexpr float SCALE = 0.17677669529663687f;   // 32^-0.5
static constexpr float LOG2E = 1.44269504088896f;
static constexpr float QSCALE = SCALE * LOG2E;         // exp2(S) = softmax exp

__device__ inline float fast_exp2(float x) {
#if __has_builtin(__builtin_amdgcn_exp2f)
    return __builtin_amdgcn_exp2f(x);
#else
    float r; asm("v_exp_f32 %0, %1" : "=v"(r) : "v"(x)); return r;
#endif
}

__device__ inline unsigned cvt_pk_bf16(float lo, float hi) {
    unsigned d;
    asm("v_cvt_pk_bf16_f32 %0, %1, %2" : "=v"(d) : "v"(lo), "v"(hi));
    return d;
}

// ---------------------------------------------------------------------------
// Kernel 1: QKV GEMM, LDS-staged, software-pipelined.
// ---------------------------------------------------------------------------
__global__ __launch_bounds__(256) void qkv_gemm(
    const float* __restrict__ X, const float* __restrict__ W,
    const float* __restrict__ Bq,
    __bf16* __restrict__ Qw, __bf16* __restrict__ Kw, __bf16* __restrict__ Vt)
{
    constexpr int LDK = 136;
    __shared__ __align__(16) __bf16 smem[128 * LDK + 64 * LDK];
    __bf16* Xs = smem;
    __bf16* Wsh = smem + 128 * LDK;

    const int bm = blockIdx.x & 63, bn = blockIdx.x >> 6;
    const int tid = threadIdx.x, wid = tid >> 6, lane = tid & 63;
    const int lr = lane & 15, lh = lane >> 4;
    const int m0b = bm * 128, n0b = bn * 64;
    const int wm0 = (wid >> 1) * 64, wn0 = (wid & 1) * 32;

    const int srow2 = lane >> 5;
    const int scol  = (lane & 31) * 4;

    f32x4 acc[4][2] = {};
    f32x4 xr[16], wr8[8];

#define LOADC(CH) do {                                                        \
    const int k0c = (CH) * 128;                                               \
    _Pragma("unroll")                                                         \
    for (int j = 0; j < 16; ++j) {                                            \
        const int row = j * 8 + wid * 2 + srow2;                              \
        xr[j] = *(const f32x4*)(X + (size_t)(m0b + row) * 256 + k0c + scol);  \
    }                                                                         \
    _Pragma("unroll")                                                         \
    for (int j = 0; j < 8; ++j) {                                             \
        const int row = j * 8 + wid * 2 + srow2;                              \
        wr8[j] = *(const f32x4*)(W + (size_t)(n0b + row) * 256 + k0c + scol); \
    }                                                                         \
} while (0)

#define WRITEC() do {                                                         \
    _Pragma("unroll")                                                         \
    for (int j = 0; j < 16; ++j) {                                            \
        const int row = j * 8 + wid * 2 + srow2;                              \
        bf16x4 cv; cv[0]=(__bf16)xr[j][0]; cv[1]=(__bf16)xr[j][1];            \
                   cv[2]=(__bf16)xr[j][2]; cv[3]=(__bf16)xr[j][3];            \
        *(bf16x4*)(&Xs[row * LDK + scol]) = cv;                               \
    }                                                                         \
    _Pragma("unroll")                                                         \
    for (int j = 0; j < 8; ++j) {                                             \
        const int row = j * 8 + wid * 2 + srow2;                              \
        bf16x4 cv; cv[0]=(__bf16)wr8[j][0]; cv[1]=(__bf16)wr8[j][1];          \
                   cv[2]=(__bf16)wr8[j][2]; cv[3]=(__bf16)wr8[j][3];          \
        *(bf16x4*)(&Wsh[row * LDK + scol]) = cv;                              \
    }                                                                         \
} while (0)

#define COMPUTEC() do {                                                       \
    _Pragma("unroll")                                                         \
    for (int ks = 0; ks < 4; ++ks) {                                          \
        bf16x8 a[4], b[2];                                                    \
        _Pragma("unroll")                                                     \
        for (int mt = 0; mt < 4; ++mt)                                        \
            a[mt] = *(const bf16x8*)(&Xs[(wm0 + mt * 16 + lr) * LDK + ks * 32 + lh * 8]); \
        _Pragma("unroll")                                                     \
        for (int nt = 0; nt < 2; ++nt)                                        \
            b[nt] = *(const bf16x8*)(&Wsh[(wn0 + nt * 16 + lr) * LDK + ks * 32 + lh * 8]); \
        _Pragma("unroll")                                                     \
        for (int mt = 0; mt < 4; ++mt)                                        \
            _Pragma("unroll")                                                 \
            for (int nt = 0; nt < 2; ++nt)                                    \
                acc[mt][nt] = MFMA16(a[mt], b[nt], acc[mt][nt]);              \
    }                                                                         \
} while (0)

    LOADC(0);
    WRITEC();
    __syncthreads();
    LOADC(1);                 // issued AFTER barrier: full compute-0 in flight
    COMPUTEC();               // chunk 0
    __syncthreads();
    WRITEC();                 // vmcnt wait covered by compute-0
    __syncthreads();
    COMPUTEC();               // chunk 1
    __syncthreads();          // all LDS reads done before epilogue scratch

#undef LOADC
#undef WRITEC
#undef COMPUTEC

    const int m0 = m0b + wm0;
    const int n0 = n0b + wn0;
    const int bb  = m0 >> 11;
    const int li0 = m0 & 2047;
    const int h = n0 / 96, r = n0 % 96;
    const int which = r >> 5;
    const int bh = bb * H + h;
    __bf16* sw = smem + wid * 2560;

    if (which == 2) {
        #pragma unroll
        for (int nt = 0; nt < 2; ++nt) {
            const float bias = Bq[n0 + nt * 16 + lr];
            #pragma unroll
            for (int mt = 0; mt < 4; ++mt)
                #pragma unroll
                for (int i = 0; i < 4; ++i)
                    sw[(nt * 16 + lr) * 72 + mt * 16 + lh * 4 + i] =
                        (__bf16)(acc[mt][nt][i] + bias);
        }
        #pragma unroll
        for (int j = 0; j < 4; ++j) {
            const int cch = lane + 64 * j;
            const int d = cch >> 3, lc = (cch & 7) * 8;
            const bf16x8 v = *(const bf16x8*)(&sw[d * 72 + lc]);
            *(bf16x8*)(Vt + ((size_t)bh * D + d) * L + li0 + lc) = v;
        }
    } else {
        const float scl = (which == 0) ? QSCALE : 1.0f;
        #pragma unroll
        for (int nt = 0; nt < 2; ++nt) {
            const float bias = Bq[n0 + nt * 16 + lr];
            #pragma unroll
            for (int mt = 0; mt < 4; ++mt)
                #pragma unroll
                for (int i = 0; i < 4; ++i)
                    sw[(mt * 16 + lh * 4 + i) * 40 + nt * 16 + lr] =
                        (__bf16)((acc[mt][nt][i] + bias) * scl);
        }
        __bf16* dst = (which == 0 ? Qw : Kw) + ((size_t)bh * L + li0) * D;
        #pragma unroll
        for (int j = 0; j < 4; ++j) {
            const int cch = lane + 64 * j;
            const bf16x8 v = *(const bf16x8*)(&sw[(cch >> 2) * 40 + (cch & 3) * 8]);
            *(bf16x8*)(dst + (size_t)cch * 8) = v;
        }
    }
}

// ---------------------------------------------------------------------------
// Kernel 2: flash attention, KV-split 2, 32x32x16 MFMA, in-register P (T12).
// grid 1024 = 32 bh x 32 qt(64 rows); 256 thr (4 waves).
// Loop order: bar -> LOADR(t+1) -> COMPUTE(cur) -> WRITEB(next).
// ---------------------------------------------------------------------------
__global__ __launch_bounds__(256, 4) void attn_fwd(
    const __bf16* __restrict__ Qw, const __bf16* __restrict__ Kw,
    const __bf16* __restrict__ Vt, __bf16* __restrict__ O)
{
    __shared__ __align__(16) __bf16 smem[19456];

    const int bid = blockIdx.x;
    const int bh = ((bid & 7) << 2) | ((bid >> 3) & 3);
    const int qt = bid >> 5;
    const int tid = threadIdx.x, wid = tid >> 6, lane = tid & 63;
    const int lo = lane & 31, hi = lane >> 5;
    const int qgroup = wid & 1, khalf = wid >> 1;
    const int q0 = qt * 64 + qgroup * 32;

    const __bf16* Qb = Qw + (size_t)bh * L * D;
    const __bf16* Kb = Kw + (size_t)bh * L * D;
    const __bf16* Vb = Vt + (size_t)bh * D * L;

    bf16x8 qf[2];
    #pragma unroll
    for (int cl = 0; cl < 2; ++cl)
        qf[cl] = *(const bf16x8*)(Qb + (size_t)(q0 + lo) * D + cl * 16 + hi * 8);

    f32x16 oacc = {};
    float sacc[4] = {0.f, 0.f, 0.f, 0.f};

    const int krow = tid >> 1, kcol = (tid & 1) * 16;
    const int khS = krow >> 6, krl = krow & 63;
    const int vrow = tid >> 2, vcol = (tid & 3) * 16;
    const int vhS = vrow >> 5, vd = vrow & 31;

    bf16x8 kA, kB, vA, vB;
#define LOADR(KV) do {                                                         \
    const __bf16* kp = Kb + (size_t)(khS * 1024 + (KV) + krl) * D + kcol;      \
    kA = *(const bf16x8*)kp;  kB = *(const bf16x8*)(kp + 8);                   \
    const __bf16* vp = Vb + (size_t)vd * L + vhS * 1024 + (KV) + vcol;         \
    vA = *(const bf16x8*)vp;  vB = *(const bf16x8*)(vp + 8);                   \
} while (0)
#define WRITEB(BUF) do {                                                       \
    __bf16* kp = smem + ((BUF) * 2 + khS) * 4864 + krl * 40 + kcol;            \
    *(bf16x8*)kp = kA;  *(bf16x8*)(kp + 8) = kB;                               \
    __bf16* vp = smem + ((BUF) * 2 + vhS) * 4864 + 2560 + vd * 72 + vcol;      \
    *(bf16x8*)vp = vA;  *(bf16x8*)(vp + 8) = vB;                               \
} while (0)

    LOADR(0);
    WRITEB(0);

    for (int t = 0; t < 16; ++t) {
        const int cur = t & 1;
        __syncthreads();                   // buf[cur] visible
        if (t + 1 < 16) LOADR((t + 1) * 64);   // issued post-barrier

        const __bf16* Kp = smem + (cur * 2 + khalf) * 4864;
        const __bf16* Vp = Kp + 2560;

        #pragma unroll
        for (int sub = 0; sub < 2; ++sub) {
            const int kb = sub * 32;

            f32x16 sst = {};
            const bf16x8 ka0 = *(const bf16x8*)(Kp + (kb + lo) * 40 + hi * 8);
            const bf16x8 ka1 = *(const bf16x8*)(Kp + (kb + lo) * 40 + 16 + hi * 8);
            sst = MFMA32(ka0, qf[0], sst);
            sst = MFMA32(ka1, qf[1], sst);

            float p[16];
            #pragma unroll
            for (int r = 0; r < 16; ++r) p[r] = fast_exp2(sst[r]);
            #pragma unroll
            for (int r = 0; r < 16; ++r) sacc[r & 3] += p[r];

            unsigned pk[8];
            #pragma unroll
            for (int j = 0; j < 8; ++j) pk[j] = cvt_pk_bf16(p[2 * j], p[2 * j + 1]);

            unsigned a0 = pk[0], b0 = pk[2];
            unsigned a1 = pk[1], b1 = pk[3];
            unsigned c0 = pk[4], d0 = pk[6];
            unsigned c1 = pk[5], d1 = pk[7];
            asm("v_permlane32_swap_b32 %0, %1" : "+v"(a0), "+v"(b0));
            asm("v_permlane32_swap_b32 %0, %1" : "+v"(a1), "+v"(b1));
            asm("v_permlane32_swap_b32 %0, %1" : "+v"(c0), "+v"(d0));
            asm("v_permlane32_swap_b32 %0, %1" : "+v"(c1), "+v"(d1));
            const u32x4 f0 = {a0, a1, b0, b1};
            const u32x4 f1 = {c0, c1, d0, d1};
            const bf16x8 pf0 = __builtin_bit_cast(bf16x8, f0);
            const bf16x8 pf1 = __builtin_bit_cast(bf16x8, f1);

            const bf16x8 vb0 = *(const bf16x8*)(Vp + lo * 72 + kb + hi * 8);
            const bf16x8 vb1 = *(const bf16x8*)(Vp + lo * 72 + kb + 16 + hi * 8);
            oacc = MFMA32(pf0, vb0, oacc);
            oacc = MFMA32(pf1, vb1, oacc);
        }

        if (t + 1 < 16) WRITEB(cur ^ 1);   // vmcnt wait covered by compute
    }
#undef LOADR
#undef WRITEB

    float tot = (sacc[0] + sacc[1]) + (sacc[2] + sacc[3]);
    tot += __shfl_xor(tot, 32);

    __syncthreads();
    float* cs = (float*)smem;
    if (khalf == 1) {
        float* p = cs + (qgroup * 64 + lane) * 20;
        #pragma unroll
        for (int r = 0; r < 16; ++r) p[r] = oacc[r];
        p[16] = tot;
    }
    __syncthreads();
    if (khalf == 0) {
        const float* p = cs + (qgroup * 64 + lane) * 20;
        #pragma unroll
        for (int r = 0; r < 16; ++r) oacc[r] += p[r];
        tot += p[16];
        const float inv = 1.f / tot;

        const int b = bh >> 3, h = bh & 7;
        #pragma unroll
        for (int r = 0; r < 16; ++r) {
            const int qr = (r & 3) + 8 * (r >> 2) + 4 * hi;
            const float rs = __shfl(inv, qr);
            O[((size_t)b * L + q0 + qr) * C + h * D + lo] = (__bf16)(oacc[r] * rs);
        }
    }
}

// ---------------------------------------------------------------------------
// Kernel 3: output projection with dense LDS staging (r19).
// ---------------------------------------------------------------------------
__global__ __launch_bounds__(256) void proj_gemm(
    const __bf16* __restrict__ A, const float* __restrict__ W,
    const float* __restrict__ Bp, float* __restrict__ Out)
{
    constexpr int LDA = 264;
    __shared__ __align__(16) __bf16 ps[2 * 64 * LDA];
    __bf16* As = ps;
    __bf16* Wsb = ps + 64 * LDA;

    const int bm = blockIdx.x & 127, bn = blockIdx.x >> 7;
    const int tid = threadIdx.x, wid = tid >> 6, lane = tid & 63;
    const int lr = lane & 15, lh = lane >> 4;
    const int m0b = bm * 64, n0b = bn * 64;
    const int wm0 = (wid >> 1) * 32, wn0 = (wid & 1) * 32;

    #pragma unroll
    for (int j = 0; j < 8; ++j) {
        const int c = tid + 256 * j;
        const int row = c >> 5, col = (c & 31) * 8;
        *(bf16x8*)(&As[row * LDA + col]) =
            *(const bf16x8*)(A + (size_t)(m0b + row) * 256 + col);
    }
    #pragma unroll
    for (int j = 0; j < 16; ++j) {
        const int c = tid + 256 * j;
        const int row = c >> 6, col = (c & 63) * 4;
        const f32x4 v = *(const f32x4*)(W + (size_t)(n0b + row) * 256 + col);
        bf16x4 cv; cv[0]=(__bf16)v[0]; cv[1]=(__bf16)v[1]; cv[2]=(__bf16)v[2]; cv[3]=(__bf16)v[3];
        *(bf16x4*)(&Wsb[row * LDA + col]) = cv;
    }
    __syncthreads();

    f32x4 acc[2][2] = {};
    #pragma unroll
    for (int k0 = 0; k0 < 256; k0 += 32) {
        bf16x8 a[2], b[2];
        #pragma unroll
        for (int mt = 0; mt < 2; ++mt)
            a[mt] = *(const bf16x8*)(&As[(wm0 + mt * 16 + lr) * LDA + k0 + lh * 8]);
        #pragma unroll
        for (int nt = 0; nt < 2; ++nt)
            b[nt] = *(const bf16x8*)(&Wsb[(wn0 + nt * 16 + lr) * LDA + k0 + lh * 8]);
        #pragma unroll
        for (int mt = 0; mt < 2; ++mt)
            #pragma unroll
            for (int nt = 0; nt < 2; ++nt)
                acc[mt][nt] = MFMA16(a[mt], b[nt], acc[mt][nt]);
    }

    #pragma unroll
    for (int mt = 0; mt < 2; ++mt) {
        #pragma unroll
        for (int nt = 0; nt < 2; ++nt) {
            const int n = n0b + wn0 + nt * 16 + lr;
            const float bias = Bp[n];
            #pragma unroll
            for (int i = 0; i < 4; ++i) {
                const int m = m0b + wm0 + mt * 16 + lh * 4 + i;
                Out[(size_t)m * 256 + n] = acc[mt][nt][i] + bias;
            }
        }
    }
}

__global__ void fatal_flag(float* Out, int n, float v) {
    int i = blockIdx.x * blockDim.x + threadIdx.x;
    if (i < n) Out[i] = (i == 0) ? v : 0.f;
}

// ---------------------------------------------------------------------------
extern "C" void kernel_launch(void* const* d_in, const int* in_sizes, int n_in,
                              void* d_out, int out_size, void* d_ws, size_t ws_size,
                              hipStream_t stream)
{
    float* out = (float*)d_out;

    const float *x = nullptr, *w_qkv = nullptr, *b_qkv = nullptr,
                *w_proj = nullptr, *b_proj = nullptr;
    for (int i = 0; i < n_in; ++i) {
        switch (in_sizes[i]) {
            case 2097152: x      = (const float*)d_in[i]; break;
            case 196608:  w_qkv  = (const float*)d_in[i]; break;
            case 768:     b_qkv  = (const float*)d_in[i]; break;
            case 65536:   w_proj = (const float*)d_in[i]; break;
            case 256:     b_proj = (const float*)d_in[i]; break;
        }
    }
    if (!x || !w_qkv || !b_qkv || !w_proj || !b_proj) {
        fatal_flag<<<dim3((out_size + 255) / 256), dim3(256), 0, stream>>>(out, out_size, 3e9f);
        return;
    }

    const size_t SEG = (size_t)Bsz * H * L * D;      // 2M elems
    if (ws_size < 4 * SEG * sizeof(__bf16)) {
        fatal_flag<<<dim3((out_size + 255) / 256), dim3(256), 0, stream>>>(out, out_size, 1e9f);
        return;
    }

    __bf16* ws = (__bf16*)d_ws;
    __bf16* Qw = ws;
    __bf16* Kw = ws + SEG;
    __bf16* Vt = ws + 2 * SEG;
    __bf16* Ob = ws + 3 * SEG;

    qkv_gemm<<<dim3(768), dim3(256), 0, stream>>>(x, w_qkv, b_qkv, Qw, Kw, Vt);
    attn_fwd<<<dim3(1024), dim3(256), 0, stream>>>(Qw, Kw, Vt, Ob);
    proj_gemm<<<dim3(512), dim3(256), 0, stream>>>(Ob, w_proj, b_proj, out);
}